// Round 12
// baseline (562.437 us; speedup 1.0000x reference)
//
#include <hip/hip_runtime.h>

#define BATCH   1048576
#define IN_DIM  64
#define OUT_DIM 16
#define TPW     2
#define NWTOT   8192   // total waves = BATCH/64/TPW; grid = NWTOT/2 blocks of 128

// ---------------------------------------------------------------------------
// Kernel 1: build At = A^T (64x16) -> ws[0:1024) and Ct = (G*A)^T (64x16)
// -> ws[1024:2048), where G = (A A^T)^-1. Gauss-Jordan w/ partial pivoting.
// Single block, 256 threads. (validated rounds 1-11)
// ---------------------------------------------------------------------------
__global__ __launch_bounds__(256) void precompute_kernel(
    const float* __restrict__ A, float* __restrict__ ws)
{
    __shared__ float sA[16][64];
    __shared__ float M[16][32];   // [S | I]
    __shared__ float fac[16];
    __shared__ int piv;

    const int tid = threadIdx.x;

    for (int i = tid; i < 1024; i += 256) sA[i >> 6][i & 63] = A[i];
    __syncthreads();

    {
        const int i = tid >> 4, j = tid & 15;
        float s = 0.f;
        #pragma unroll
        for (int k = 0; k < 64; ++k) s = fmaf(sA[i][k], sA[j][k], s);
        M[i][j] = s;
        M[i][16 + j] = (i == j) ? 1.f : 0.f;
    }
    __syncthreads();

    for (int p = 0; p < 16; ++p) {
        if (tid == 0) {
            int best = p;
            float bv = fabsf(M[p][p]);
            for (int r = p + 1; r < 16; ++r) {
                float v = fabsf(M[r][p]);
                if (v > bv) { bv = v; best = r; }
            }
            piv = best;
        }
        __syncthreads();
        if (tid < 32) {
            const int pr = piv;
            if (pr != p) { float t = M[p][tid]; M[p][tid] = M[pr][tid]; M[pr][tid] = t; }
        }
        __syncthreads();
        const float pv = M[p][p];
        __syncthreads();
        if (tid < 32) M[p][tid] *= (1.0f / pv);
        __syncthreads();
        if (tid < 16) fac[tid] = M[tid][p];
        __syncthreads();
        for (int e = tid; e < 512; e += 256) {
            const int r = e >> 5, c = e & 31;
            if (r != p) M[r][c] = fmaf(-fac[r], M[p][c], M[r][c]);
        }
        __syncthreads();
    }

    // At[k*16 + j] = A[j][k]
    for (int e = tid; e < 1024; e += 256) {
        const int k = e >> 4, j = e & 15;
        ws[e] = sA[j][k];
    }
    // Ct[k*16 + i] = C[i][k] = sum_j G[i][j] * A[j][k]
    for (int e = tid; e < 1024; e += 256) {
        const int k = e >> 4, i = e & 15;
        float s = 0.f;
        #pragma unroll
        for (int j = 0; j < 16; ++j) s = fmaf(M[i][16 + j], sA[j][k], s);
        ws[1024 + e] = s;
    }
}

// ---------------------------------------------------------------------------
// Kernel 2: x = y - C^T (A y - b), thread-per-row. Full 16 KB y-tile in LDS
// (both k-halves; no register capture, no re-read). ONE rotating g[8]
// staging buffer keeps the live set ~60 VGPR by construction; cross-half AND
// cross-tile prefetch keeps ~8 KB of loads in flight during every compute
// phase (anti-convoy); sched_barrier(0) pins each issue group so the
// compiler cannot sink loads (the R11 failure). b is loaded BEFORE issuing
// H1 (vmcnt is FIFO: waiting on b must not drain H1). 128-thread blocks:
// 32 KB LDS -> 5 blocks/CU = 10 waves/CU. Stores are direct per-lane
// (R1-R4: WRITE_SIZE stays at the 262 MB ideal). Matrices ride SMEM/K$.
// ---------------------------------------------------------------------------
__global__ __launch_bounds__(128, 2) void apply_kernel(
    const float* __restrict__ y, const float* __restrict__ b,
    const float* __restrict__ ws, float* __restrict__ out)
{
    __shared__ float4 buf[2][64][16];   // 32 KB per 2-wave block

    const int tid  = threadIdx.x;
    const int wv   = tid >> 6;
    const int l    = tid & 63;
    const int srow = l >> 3;            // 0..7
    const int ssl  = l & 7;             // 0..7

    const float4* __restrict__ At4 = reinterpret_cast<const float4*>(ws);        // At[k][j]: k*4+jq
    const float4* __restrict__ Ct4 = reinterpret_cast<const float4*>(ws + 1024); // Ct[k][i]: k*4+iq

    const size_t W = (size_t)blockIdx.x * 2 + wv;   // wave global id
    size_t rowbase = W * 64;

    // ---- prologue: issue H0(tile 0) ----
    float4 g[8];
    {
        const float* yb = y + rowbase * 64;
        #pragma unroll
        for (int i = 0; i < 8; ++i)
            g[i] = *reinterpret_cast<const float4*>(yb + (i * 8 + srow) * 64 + ssl * 4);
    }

    #pragma unroll
    for (int s = 0; s < TPW; ++s) {
        const float*  ybs = y   + rowbase * 64;
        float*        obs = out + rowbase * 64;
        const float4* b4  = reinterpret_cast<const float4*>(b) + (rowbase + l) * 4;

        // ---- commit H0 to LDS (waits vmcnt for g) ----
        #pragma unroll
        for (int i = 0; i < 8; ++i) {
            const int row = i * 8 + srow;
            buf[wv][row][ssl ^ (row & 7)] = g[i];
        }
        // ---- load b (BEFORE H1 issue: FIFO vmcnt) ----
        const float4 bv0 = b4[0], bv1 = b4[1], bv2 = b4[2], bv3 = b4[3];
        // ---- issue H1 (in flight during p1-H0) ----
        #pragma unroll
        for (int i = 0; i < 8; ++i)
            g[i] = *reinterpret_cast<const float4*>(ybs + (i * 8 + srow) * 64 + 32 + ssl * 4);
        __builtin_amdgcn_sched_barrier(0);

        float t[16];
        t[ 0] = -bv0.x; t[ 1] = -bv0.y; t[ 2] = -bv0.z; t[ 3] = -bv0.w;
        t[ 4] = -bv1.x; t[ 5] = -bv1.y; t[ 6] = -bv1.z; t[ 7] = -bv1.w;
        t[ 8] = -bv2.x; t[ 9] = -bv2.y; t[10] = -bv2.z; t[11] = -bv2.w;
        t[12] = -bv3.x; t[13] = -bv3.y; t[14] = -bv3.z; t[15] = -bv3.w;

        // ---- phase 1, half 0 (k=0:32) ----
        #pragma unroll
        for (int q = 0; q < 8; ++q) {
            const float4 yv = buf[wv][l][q ^ (l & 7)];
            #pragma unroll
            for (int dk = 0; dk < 4; ++dk) {
                const float yk = (dk == 0) ? yv.x : (dk == 1) ? yv.y :
                                 (dk == 2) ? yv.z : yv.w;
                const int k = q * 4 + dk;
                #pragma unroll
                for (int jq = 0; jq < 4; ++jq) {
                    const float4 a = At4[k * 4 + jq];
                    t[4*jq+0] = fmaf(a.x, yk, t[4*jq+0]);
                    t[4*jq+1] = fmaf(a.y, yk, t[4*jq+1]);
                    t[4*jq+2] = fmaf(a.z, yk, t[4*jq+2]);
                    t[4*jq+3] = fmaf(a.w, yk, t[4*jq+3]);
                }
            }
        }

        // ---- commit H1 to LDS ----
        #pragma unroll
        for (int i = 0; i < 8; ++i) {
            const int row = i * 8 + srow;
            buf[wv][row][8 + (ssl ^ (row & 7))] = g[i];
        }
        // ---- issue next tile's H0 (in flight during p1-H1 + p2) ----
        if (s + 1 < TPW) {
            const float* yn = y + (rowbase + (size_t)NWTOT * 64) * 64;
            #pragma unroll
            for (int i = 0; i < 8; ++i)
                g[i] = *reinterpret_cast<const float4*>(yn + (i * 8 + srow) * 64 + ssl * 4);
        }
        __builtin_amdgcn_sched_barrier(0);

        // ---- phase 1, half 1 (k=32:64): t complete ----
        #pragma unroll
        for (int q = 0; q < 8; ++q) {
            const float4 yv = buf[wv][l][8 + (q ^ (l & 7))];
            #pragma unroll
            for (int dk = 0; dk < 4; ++dk) {
                const float yk = (dk == 0) ? yv.x : (dk == 1) ? yv.y :
                                 (dk == 2) ? yv.z : yv.w;
                const int k = 32 + q * 4 + dk;
                #pragma unroll
                for (int jq = 0; jq < 4; ++jq) {
                    const float4 a = At4[k * 4 + jq];
                    t[4*jq+0] = fmaf(a.x, yk, t[4*jq+0]);
                    t[4*jq+1] = fmaf(a.y, yk, t[4*jq+1]);
                    t[4*jq+2] = fmaf(a.z, yk, t[4*jq+2]);
                    t[4*jq+3] = fmaf(a.w, yk, t[4*jq+3]);
                }
            }
        }

        // ---- phase 2, half 0: x[0:32], direct per-lane store ----
        #pragma unroll
        for (int q = 0; q < 8; ++q) {
            const float4 yv = buf[wv][l][q ^ (l & 7)];
            float xv[4];
            #pragma unroll
            for (int dk = 0; dk < 4; ++dk) {
                const int k = q * 4 + dk;
                float x = (dk == 0) ? yv.x : (dk == 1) ? yv.y :
                          (dk == 2) ? yv.z : yv.w;
                #pragma unroll
                for (int iq = 0; iq < 4; ++iq) {
                    const float4 c = Ct4[k * 4 + iq];
                    x = fmaf(-c.x, t[4*iq+0], x);
                    x = fmaf(-c.y, t[4*iq+1], x);
                    x = fmaf(-c.z, t[4*iq+2], x);
                    x = fmaf(-c.w, t[4*iq+3], x);
                }
                xv[dk] = x;
            }
            *reinterpret_cast<float4*>(obs + l * 64 + q * 4) =
                make_float4(xv[0], xv[1], xv[2], xv[3]);
        }

        // ---- phase 2, half 1: x[32:64] ----
        #pragma unroll
        for (int q = 0; q < 8; ++q) {
            const float4 yv = buf[wv][l][8 + (q ^ (l & 7))];
            float xv[4];
            #pragma unroll
            for (int dk = 0; dk < 4; ++dk) {
                const int k = 32 + q * 4 + dk;
                float x = (dk == 0) ? yv.x : (dk == 1) ? yv.y :
                          (dk == 2) ? yv.z : yv.w;
                #pragma unroll
                for (int iq = 0; iq < 4; ++iq) {
                    const float4 c = Ct4[k * 4 + iq];
                    x = fmaf(-c.x, t[4*iq+0], x);
                    x = fmaf(-c.y, t[4*iq+1], x);
                    x = fmaf(-c.z, t[4*iq+2], x);
                    x = fmaf(-c.w, t[4*iq+3], x);
                }
                xv[dk] = x;
            }
            *reinterpret_cast<float4*>(obs + l * 64 + 32 + q * 4) =
                make_float4(xv[0], xv[1], xv[2], xv[3]);
        }

        rowbase += (size_t)NWTOT * 64;
    }
}

// ---------------------------------------------------------------------------
extern "C" void kernel_launch(void* const* d_in, const int* in_sizes, int n_in,
                              void* d_out, int out_size, void* d_ws, size_t ws_size,
                              hipStream_t stream) {
    const float* y = (const float*)d_in[0];   // (1048576, 64)
    const float* A = (const float*)d_in[1];   // (16, 64)
    const float* b = (const float*)d_in[2];   // (1048576, 16)
    float* out = (float*)d_out;               // (1048576, 64)
    float* ws  = (float*)d_ws;                // 2048 floats: At(1024) + Ct(1024)

    precompute_kernel<<<1, 256, 0, stream>>>(A, ws);
    apply_kernel<<<NWTOT / 2, 128, 0, stream>>>(y, b, ws, out);
}

// Round 13
// 232.774 us; speedup vs baseline: 2.4162x; 2.4162x over previous
//
#include <hip/hip_runtime.h>

#define BATCH   1048576
#define IN_DIM  64
#define OUT_DIM 16
#define TP      20        // padded LDS row stride (floats): conflict-spread, 16B-aligned

typedef __attribute__((ext_vector_type(8))) short short8;  // 8 bf16 = 4 VGPR
typedef __attribute__((ext_vector_type(4))) float f32x4;   // MFMA accumulator

// ---------------------------------------------------------------------------
// Kernel 1: Ct = (G*A)^T (64x16 row-major) -> ws[0:1024), G = (A A^T)^-1.
// Gauss-Jordan w/ partial pivoting (validated rounds 1-12).
// ---------------------------------------------------------------------------
__global__ __launch_bounds__(256) void precompute_kernel(
    const float* __restrict__ A, float* __restrict__ ws)
{
    __shared__ float sA[16][64];
    __shared__ float M[16][32];   // [S | I]
    __shared__ float fac[16];
    __shared__ int piv;

    const int tid = threadIdx.x;

    for (int i = tid; i < 1024; i += 256) sA[i >> 6][i & 63] = A[i];
    __syncthreads();

    {
        const int i = tid >> 4, j = tid & 15;
        float s = 0.f;
        #pragma unroll
        for (int k = 0; k < 64; ++k) s = fmaf(sA[i][k], sA[j][k], s);
        M[i][j] = s;
        M[i][16 + j] = (i == j) ? 1.f : 0.f;
    }
    __syncthreads();

    for (int p = 0; p < 16; ++p) {
        if (tid == 0) {
            int best = p;
            float bv = fabsf(M[p][p]);
            for (int r = p + 1; r < 16; ++r) {
                float v = fabsf(M[r][p]);
                if (v > bv) { bv = v; best = r; }
            }
            piv = best;
        }
        __syncthreads();
        if (tid < 32) {
            const int pr = piv;
            if (pr != p) { float t = M[p][tid]; M[p][tid] = M[pr][tid]; M[pr][tid] = t; }
        }
        __syncthreads();
        const float pv = M[p][p];
        __syncthreads();
        if (tid < 32) M[p][tid] *= (1.0f / pv);
        __syncthreads();
        if (tid < 16) fac[tid] = M[tid][p];
        __syncthreads();
        for (int e = tid; e < 512; e += 256) {
            const int r = e >> 5, c = e & 31;
            if (r != p) M[r][c] = fmaf(-fac[r], M[p][c], M[r][c]);
        }
        __syncthreads();
    }

    // Ct[k*16 + i] = C[i][k] = sum_j G[i][j] * A[j][k]
    for (int e = tid; e < 1024; e += 256) {
        const int k = e >> 4, i = e & 15;
        float s = 0.f;
        #pragma unroll
        for (int j = 0; j < 16; ++j) s = fmaf(M[i][16 + j], sA[j][k], s);
        ws[e] = s;
    }
}

// ---------------------------------------------------------------------------
// bf16 truncation-split packing. hi = top 16 bits of f32 (exact float);
// lo = bf16(v - hi_as_f32). hi*hi products are exact in f32 MFMA.
// ---------------------------------------------------------------------------
__device__ __forceinline__ unsigned pack2(float a, float b, bool lo) {
    unsigned ua = __float_as_uint(a), ub = __float_as_uint(b);
    if (lo) {
        ua = __float_as_uint(a - __uint_as_float(ua & 0xFFFF0000u));
        ub = __float_as_uint(b - __uint_as_float(ub & 0xFFFF0000u));
    }
    return (ua >> 16) | (ub & 0xFFFF0000u);
}
__device__ __forceinline__ short8 pack8(float4 p, float4 q, bool lo) {
    union { short8 s; unsigned u[4]; } r;
    r.u[0] = pack2(p.x, p.y, lo);
    r.u[1] = pack2(p.z, p.w, lo);
    r.u[2] = pack2(q.x, q.y, lo);
    r.u[3] = pack2(q.z, q.w, lo);
    return r.s;
}

#define MF(a, bb, cc) __builtin_amdgcn_mfma_f32_16x16x32_bf16((a), (bb), (cc), 0, 0, 0)

// A-frag of Y for (mb, c): lane holds Y[mb*16+lh][c*16 + hf*8 .. +7], hi or lo half.
#define YFRAG(mb, c) pack8( \
    y4[(wbase + (mb)*16 + lh)*16 + (c)*4 + hf*2], \
    y4[(wbase + (mb)*16 + lh)*16 + (c)*4 + hf*2 + 1], lolane)

#define G1(mb, ACC) { \
    short8 af; \
    af = YFRAG(mb, 0); ACC = MF(af, B1_0, ACC); ACC = MF(af, B2_0, ACC); \
    af = YFRAG(mb, 1); ACC = MF(af, B1_1, ACC); ACC = MF(af, B2_1, ACC); \
    af = YFRAG(mb, 2); ACC = MF(af, B1_2, ACC); ACC = MF(af, B2_2, ACC); \
    af = YFRAG(mb, 3); ACC = MF(af, B1_3, ACC); ACC = MF(af, B2_3, ACC); }

#define TWRITE(mb, ACC) { \
    tb[wv][((mb)*16 + 4*lg + 0)*TP + lh] = ACC[0]; \
    tb[wv][((mb)*16 + 4*lg + 1)*TP + lh] = ACC[1]; \
    tb[wv][((mb)*16 + 4*lg + 2)*TP + lh] = ACC[2]; \
    tb[wv][((mb)*16 + 4*lg + 3)*TP + lh] = ACC[3]; }

#define TFRAG(mb) ({ \
    float4 t0 = *(const float4*)&tb[wv][((mb)*16 + lh)*TP + hf*8]; \
    float4 t1 = *(const float4*)&tb[wv][((mb)*16 + lh)*TP + hf*8 + 4]; \
    const float4 g0 = b4[(wbase + (mb)*16 + lh)*4 + hf*2]; \
    const float4 g1 = b4[(wbase + (mb)*16 + lh)*4 + hf*2 + 1]; \
    t0.x -= g0.x; t0.y -= g0.y; t0.z -= g0.z; t0.w -= g0.w; \
    t1.x -= g1.x; t1.y -= g1.y; t1.z -= g1.z; t1.w -= g1.w; \
    pack8(t0, t1, lolane); })

#define XWRITE(mb, ACC) { \
    xb[wv][((mb)*16 + 4*lg + 0)*TP + lh] = ACC[0]; \
    xb[wv][((mb)*16 + 4*lg + 1)*TP + lh] = ACC[1]; \
    xb[wv][((mb)*16 + 4*lg + 2)*TP + lh] = ACC[2]; \
    xb[wv][((mb)*16 + 4*lg + 3)*TP + lh] = ACC[3]; }

#define XOUT(i, nb) { \
    const int row = (i)*16 + (l >> 2); \
    const int cc  = (l & 3) * 4; \
    const float4 v  = *(const float4*)&xb[wv][row*TP + cc]; \
    const float4 yy = y4[(wbase + row)*16 + (nb)*4 + (l & 3)]; \
    float4 xo; \
    xo.x = yy.x - v.x; xo.y = yy.y - v.y; xo.z = yy.z - v.z; xo.w = yy.w - v.w; \
    o4[(wbase + row)*16 + (nb)*4 + (l & 3)] = xo; }

#define G2(nb, C1n, C2n) { \
    f32x4 a0 = {0.f,0.f,0.f,0.f}, a1 = {0.f,0.f,0.f,0.f}; \
    f32x4 a2 = {0.f,0.f,0.f,0.f}, a3 = {0.f,0.f,0.f,0.f}; \
    a0 = MF(TF0, C1n, a0); a0 = MF(TF0, C2n, a0); \
    a1 = MF(TF1, C1n, a1); a1 = MF(TF1, C2n, a1); \
    a2 = MF(TF2, C1n, a2); a2 = MF(TF2, C2n, a2); \
    a3 = MF(TF3, C1n, a3); a3 = MF(TF3, C2n, a3); \
    XWRITE(0, a0); XWRITE(1, a1); XWRITE(2, a2); XWRITE(3, a3); \
    XOUT(0, nb); XOUT(1, nb); XOUT(2, nb); XOUT(3, nb); }

// ---------------------------------------------------------------------------
// Kernel 2 (MFMA): T = Y*At (hi/lo bf16 split), t = T - b via LDS transpose,
// X = Y - T*C. A- and C-fragments live in VGPRs, loaded ONCE per kernel.
// Layouts (family-consistent with m89-verified D: col=lane&15, row=4*(l>>4)+r):
//   A-frag: row = l&15, k = 8*(l>>4)+r;  B-frag: col = l&15, k = 8*(l>>4)+r.
// K=32 packs [hi(16) | lo(16)]: B1=[Mh;Mh], B2=[Ml;0] -> hh+lh+hl per 2 MFMAs.
// LDS = 40KB/block -> exactly 4 blocks/CU -> allocator targets 128 VGPR
// (kills the spill-toward-64 failure of R9/R10/R12). Wave-private buffers,
// no barriers.
// ---------------------------------------------------------------------------
__global__ __launch_bounds__(256, 4) void apply_kernel(
    const float* __restrict__ y, const float* __restrict__ b,
    const float* __restrict__ A, const float* __restrict__ ws,
    float* __restrict__ out)
{
    __shared__ float tb[4][64 * TP];   // 20 KB: t tiles (5 KB/wave)
    __shared__ float xb[4][64 * TP];   // 20 KB: X strips (5 KB/wave)

    const int tid = threadIdx.x;
    const int wv = tid >> 6, l = tid & 63;
    const int lh = l & 15, lg = l >> 4;
    const int hf = lg & 1;
    const bool lolane = (lg >= 2);

    const float4* __restrict__ y4  = reinterpret_cast<const float4*>(y);
    const float4* __restrict__ b4  = reinterpret_cast<const float4*>(b);
    const float4* __restrict__ A4  = reinterpret_cast<const float4*>(A);
    const float4* __restrict__ Ct4 = reinterpret_cast<const float4*>(ws);
    float4* __restrict__ o4        = reinterpret_cast<float4*>(out);

    union { short8 s; unsigned u[4]; } zz;
    zz.u[0] = zz.u[1] = zz.u[2] = zz.u[3] = 0u;
    const short8 zero = zz.s;

    // ---- persistent B-operand fragments (loaded once) ----
    // GEMM1: B1_c = [Ah;Ah], B2_c = [Al;0] for k-chunk c.
    short8 B1_0, B1_1, B1_2, B1_3, B2_0, B2_1, B2_2, B2_3;
    {
        float4 a0, a1;
        a0 = A4[lh*16 + 0*4 + hf*2]; a1 = A4[lh*16 + 0*4 + hf*2 + 1];
        B1_0 = pack8(a0, a1, false); B2_0 = (lg < 2) ? pack8(a0, a1, true) : zero;
        a0 = A4[lh*16 + 1*4 + hf*2]; a1 = A4[lh*16 + 1*4 + hf*2 + 1];
        B1_1 = pack8(a0, a1, false); B2_1 = (lg < 2) ? pack8(a0, a1, true) : zero;
        a0 = A4[lh*16 + 2*4 + hf*2]; a1 = A4[lh*16 + 2*4 + hf*2 + 1];
        B1_2 = pack8(a0, a1, false); B2_2 = (lg < 2) ? pack8(a0, a1, true) : zero;
        a0 = A4[lh*16 + 3*4 + hf*2]; a1 = A4[lh*16 + 3*4 + hf*2 + 1];
        B1_3 = pack8(a0, a1, false); B2_3 = (lg < 2) ? pack8(a0, a1, true) : zero;
    }
    // GEMM2: C1_n = [Ch;Ch], C2_n = [Cl;0]; C[j][col] = Ct[col][j].
    short8 C1_0, C1_1, C1_2, C1_3, C2_0, C2_1, C2_2, C2_3;
    {
        float4 c0, c1;
        c0 = Ct4[(0*16+lh)*4 + hf*2]; c1 = Ct4[(0*16+lh)*4 + hf*2 + 1];
        C1_0 = pack8(c0, c1, false); C2_0 = (lg < 2) ? pack8(c0, c1, true) : zero;
        c0 = Ct4[(1*16+lh)*4 + hf*2]; c1 = Ct4[(1*16+lh)*4 + hf*2 + 1];
        C1_1 = pack8(c0, c1, false); C2_1 = (lg < 2) ? pack8(c0, c1, true) : zero;
        c0 = Ct4[(2*16+lh)*4 + hf*2]; c1 = Ct4[(2*16+lh)*4 + hf*2 + 1];
        C1_2 = pack8(c0, c1, false); C2_2 = (lg < 2) ? pack8(c0, c1, true) : zero;
        c0 = Ct4[(3*16+lh)*4 + hf*2]; c1 = Ct4[(3*16+lh)*4 + hf*2 + 1];
        C1_3 = pack8(c0, c1, false); C2_3 = (lg < 2) ? pack8(c0, c1, true) : zero;
    }

    // ---- 4 tiles per wave, stride = total waves (4096) ----
    size_t wgid = (size_t)blockIdx.x * 4 + wv;
    #pragma unroll 1
    for (int s = 0; s < 4; ++s, wgid += 4096) {
        const size_t wbase = wgid * 64;

        // GEMM1: acc[mb] = Y * At  (K = 64 over 4 chunks, 2 MFMAs each)
        f32x4 ac0 = {0.f,0.f,0.f,0.f}, ac1 = {0.f,0.f,0.f,0.f};
        f32x4 ac2 = {0.f,0.f,0.f,0.f}, ac3 = {0.f,0.f,0.f,0.f};
        G1(0, ac0); G1(1, ac1); G1(2, ac2); G1(3, ac3);

        // t tile -> LDS (D-layout scatter), then A-layout gather minus b.
        TWRITE(0, ac0); TWRITE(1, ac1); TWRITE(2, ac2); TWRITE(3, ac3);
        const short8 TF0 = TFRAG(0);
        const short8 TF1 = TFRAG(1);
        const short8 TF2 = TFRAG(2);
        const short8 TF3 = TFRAG(3);

        // GEMM2 + fused out-transpose: X = Y - T*C, strip by strip.
        G2(0, C1_0, C2_0);
        G2(1, C1_1, C2_1);
        G2(2, C1_2, C2_2);
        G2(3, C1_3, C2_3);
    }
}

// ---------------------------------------------------------------------------
extern "C" void kernel_launch(void* const* d_in, const int* in_sizes, int n_in,
                              void* d_out, int out_size, void* d_ws, size_t ws_size,
                              hipStream_t stream) {
    const float* y = (const float*)d_in[0];   // (1048576, 64)
    const float* A = (const float*)d_in[1];   // (16, 64)
    const float* b = (const float*)d_in[2];   // (1048576, 16)
    float* out = (float*)d_out;               // (1048576, 64)
    float* ws  = (float*)d_ws;                // 1024 floats: Ct (64x16)

    precompute_kernel<<<1, 256, 0, stream>>>(A, ws);
    // 1024 blocks x 4 waves = 4096 waves, 4 tiles each, 64 rows/tile.
    apply_kernel<<<1024, 256, 0, stream>>>(y, b, A, ws, out);
}

// Round 14
// 140.601 us; speedup vs baseline: 4.0002x; 1.6556x over previous
//
#include <hip/hip_runtime.h>

#define BATCH   1048576
#define IN_DIM  64
#define OUT_DIM 16
#define NWAVE   4096      // 1024 blocks x 4 waves, all resident (4 blocks/CU)
#define TPERW   16        // 65536 16-row tiles / 4096 waves

typedef __attribute__((ext_vector_type(8))) short short8;  // 8 bf16 = 4 VGPR
typedef __attribute__((ext_vector_type(4))) float f32x4;   // MFMA accumulator

// ---------------------------------------------------------------------------
// Kernel 1: Ct[k*16+i] = C[i][k] where C = (A A^T)^-1 A  (validated R1-R13).
// ---------------------------------------------------------------------------
__global__ __launch_bounds__(256) void precompute_kernel(
    const float* __restrict__ A, float* __restrict__ ws)
{
    __shared__ float sA[16][64];
    __shared__ float M[16][32];   // [S | I]
    __shared__ float fac[16];
    __shared__ int piv;

    const int tid = threadIdx.x;

    for (int i = tid; i < 1024; i += 256) sA[i >> 6][i & 63] = A[i];
    __syncthreads();

    {
        const int i = tid >> 4, j = tid & 15;
        float s = 0.f;
        #pragma unroll
        for (int k = 0; k < 64; ++k) s = fmaf(sA[i][k], sA[j][k], s);
        M[i][j] = s;
        M[i][16 + j] = (i == j) ? 1.f : 0.f;
    }
    __syncthreads();

    for (int p = 0; p < 16; ++p) {
        if (tid == 0) {
            int best = p;
            float bv = fabsf(M[p][p]);
            for (int r = p + 1; r < 16; ++r) {
                float v = fabsf(M[r][p]);
                if (v > bv) { bv = v; best = r; }
            }
            piv = best;
        }
        __syncthreads();
        if (tid < 32) {
            const int pr = piv;
            if (pr != p) { float t = M[p][tid]; M[p][tid] = M[pr][tid]; M[pr][tid] = t; }
        }
        __syncthreads();
        const float pv = M[p][p];
        __syncthreads();
        if (tid < 32) M[p][tid] *= (1.0f / pv);
        __syncthreads();
        if (tid < 16) fac[tid] = M[tid][p];
        __syncthreads();
        for (int e = tid; e < 512; e += 256) {
            const int r = e >> 5, c = e & 31;
            if (r != p) M[r][c] = fmaf(-fac[r], M[p][c], M[r][c]);
        }
        __syncthreads();
    }

    for (int e = tid; e < 1024; e += 256) {
        const int k = e >> 4, i = e & 15;
        float s = 0.f;
        #pragma unroll
        for (int j = 0; j < 16; ++j) s = fmaf(M[i][16 + j], sA[j][k], s);
        ws[e] = s;
    }
}

// ---------------------------------------------------------------------------
// bf16 truncation-split packing (validated R13). hi*hi exact in f32 MFMA.
// ---------------------------------------------------------------------------
__device__ __forceinline__ unsigned pack2(float a, float b, bool lo) {
    unsigned ua = __float_as_uint(a), ub = __float_as_uint(b);
    if (lo) {
        ua = __float_as_uint(a - __uint_as_float(ua & 0xFFFF0000u));
        ub = __float_as_uint(b - __uint_as_float(ub & 0xFFFF0000u));
    }
    return (ua >> 16) | (ub & 0xFFFF0000u);
}
__device__ __forceinline__ short8 pack8(float4 p, float4 q, bool lo) {
    union { short8 s; unsigned u[4]; } r;
    r.u[0] = pack2(p.x, p.y, lo);
    r.u[1] = pack2(p.z, p.w, lo);
    r.u[2] = pack2(q.x, q.y, lo);
    r.u[3] = pack2(q.z, q.w, lo);
    return r.s;
}

#define MF(a, bb, cc) __builtin_amdgcn_mfma_f32_16x16x32_bf16((a), (bb), (cc), 0, 0, 0)

// ---------------------------------------------------------------------------
// Kernel 2 (MFMA, validated math of R13 + coalesced memory of R7):
//   per 16-row tile: T = Y*At (hi/lo bf16, 8 MFMA), t = T - b (LDS
//   transpose), X = y - t*C (8 MFMA seeded with y, C pre-negated), X
//   overwrites the y-tile in LDS, coalesced 1KB stores.
// A/C fragments: 64 persistent VGPRs, loaded ONCE (deletes the R7 plateau's
// 512-s_load-per-tile matrix delivery). All global access 1KB coalesced.
// Wave-private LDS (6.75KB/wave), no barriers. 27KB/block; VGPR~112 ->
// 4 waves/EU, 16 waves/CU.
// ---------------------------------------------------------------------------
__global__ __launch_bounds__(256, 4) void apply_kernel(
    const float* __restrict__ y, const float* __restrict__ b,
    const float* __restrict__ A, const float* __restrict__ ws,
    float* __restrict__ out)
{
    __shared__ float4 yT[4][16][17];   // y tile (row-major float4, pad 17)
    __shared__ float4 bT[4][16][5];    // b tile
    __shared__ float  tb[4][16 * 20];  // t = Y*At (16x16, stride 20)

    const int tid = threadIdx.x;
    const int wv = tid >> 6, l = tid & 63;
    const int lh = l & 15, lg = l >> 4;
    const int hf = lg & 1;
    const bool lolane = (lg >= 2);

    const float4* __restrict__ y4  = reinterpret_cast<const float4*>(y);
    const float4* __restrict__ b4  = reinterpret_cast<const float4*>(b);
    const float4* __restrict__ A4  = reinterpret_cast<const float4*>(A);
    const float4* __restrict__ Ct4 = reinterpret_cast<const float4*>(ws);
    float4* __restrict__ o4        = reinterpret_cast<float4*>(out);

    union { short8 s; unsigned u[4]; } zz;
    zz.u[0] = zz.u[1] = zz.u[2] = zz.u[3] = 0u;
    const short8 zero = zz.s;

    // ---- persistent fragments, loaded once ----
    // GEMM1 B-operand (At): B1_c=[Ah|Ah], B2_c=[Al|0].
    short8 B1_0, B1_1, B1_2, B1_3, B2_0, B2_1, B2_2, B2_3;
    {
        float4 a0, a1;
        a0 = A4[lh*16 + 0*4 + hf*2]; a1 = A4[lh*16 + 0*4 + hf*2 + 1];
        B1_0 = pack8(a0, a1, false); B2_0 = (lg < 2) ? pack8(a0, a1, true) : zero;
        a0 = A4[lh*16 + 1*4 + hf*2]; a1 = A4[lh*16 + 1*4 + hf*2 + 1];
        B1_1 = pack8(a0, a1, false); B2_1 = (lg < 2) ? pack8(a0, a1, true) : zero;
        a0 = A4[lh*16 + 2*4 + hf*2]; a1 = A4[lh*16 + 2*4 + hf*2 + 1];
        B1_2 = pack8(a0, a1, false); B2_2 = (lg < 2) ? pack8(a0, a1, true) : zero;
        a0 = A4[lh*16 + 3*4 + hf*2]; a1 = A4[lh*16 + 3*4 + hf*2 + 1];
        B1_3 = pack8(a0, a1, false); B2_3 = (lg < 2) ? pack8(a0, a1, true) : zero;
    }
    // GEMM2 B-operand (C), NEGATED so acc-seeded-with-y gives X directly.
    short8 C1_0, C1_1, C1_2, C1_3, C2_0, C2_1, C2_2, C2_3;
    {
        float4 c0, c1;
        #define LOADC(n) \
            c0 = Ct4[((n)*16+lh)*4 + hf*2]; c1 = Ct4[((n)*16+lh)*4 + hf*2 + 1]; \
            c0.x=-c0.x; c0.y=-c0.y; c0.z=-c0.z; c0.w=-c0.w; \
            c1.x=-c1.x; c1.y=-c1.y; c1.z=-c1.z; c1.w=-c1.w; \
            C1_##n = pack8(c0, c1, false); \
            C2_##n = (lg < 2) ? pack8(c0, c1, true) : zero;
        LOADC(0) LOADC(1) LOADC(2) LOADC(3)
        #undef LOADC
    }

    size_t tile = (size_t)blockIdx.x * 4 + wv;   // 16-row tile index
    #pragma unroll 1
    for (int s = 0; s < TPERW; ++s, tile += NWAVE) {
        const float4* ysrc = y4 + tile * 256;

        // ---- 1. coalesced loads: 4x1KB y + 1x1KB b ----
        const float4 g0 = ysrc[l];
        const float4 g1 = ysrc[64 + l];
        const float4 g2 = ysrc[128 + l];
        const float4 g3 = ysrc[192 + l];
        const float4 gb = b4[tile * 64 + l];

        // ---- 2. stage to LDS (row = i*4+lg, q = lh) ----
        yT[wv][0*4 + lg][lh] = g0;
        yT[wv][1*4 + lg][lh] = g1;
        yT[wv][2*4 + lg][lh] = g2;
        yT[wv][3*4 + lg][lh] = g3;
        bT[wv][l >> 2][l & 3] = gb;

        // ---- 3. GEMM1: acc = Y * At  (K=64, 4 chunks x 2 MFMA) ----
        f32x4 acc = {0.f, 0.f, 0.f, 0.f};
        {
            short8 af;
            float4 f0, f1;
            f0 = yT[wv][lh][0*4 + hf*2]; f1 = yT[wv][lh][0*4 + hf*2 + 1];
            af = pack8(f0, f1, lolane);
            acc = MF(af, B1_0, acc); acc = MF(af, B2_0, acc);
            f0 = yT[wv][lh][1*4 + hf*2]; f1 = yT[wv][lh][1*4 + hf*2 + 1];
            af = pack8(f0, f1, lolane);
            acc = MF(af, B1_1, acc); acc = MF(af, B2_1, acc);
            f0 = yT[wv][lh][2*4 + hf*2]; f1 = yT[wv][lh][2*4 + hf*2 + 1];
            af = pack8(f0, f1, lolane);
            acc = MF(af, B1_2, acc); acc = MF(af, B2_2, acc);
            f0 = yT[wv][lh][3*4 + hf*2]; f1 = yT[wv][lh][3*4 + hf*2 + 1];
            af = pack8(f0, f1, lolane);
            acc = MF(af, B1_3, acc); acc = MF(af, B2_3, acc);
        }

        // ---- 4. t tile: D-layout scatter, A-layout gather, minus b ----
        tb[wv][(4*lg + 0)*20 + lh] = acc[0];
        tb[wv][(4*lg + 1)*20 + lh] = acc[1];
        tb[wv][(4*lg + 2)*20 + lh] = acc[2];
        tb[wv][(4*lg + 3)*20 + lh] = acc[3];
        short8 TF;
        {
            float4 t0 = *reinterpret_cast<const float4*>(&tb[wv][lh*20 + hf*8]);
            float4 t1 = *reinterpret_cast<const float4*>(&tb[wv][lh*20 + hf*8 + 4]);
            const float4 bb0 = bT[wv][lh][hf*2];
            const float4 bb1 = bT[wv][lh][hf*2 + 1];
            t0.x -= bb0.x; t0.y -= bb0.y; t0.z -= bb0.z; t0.w -= bb0.w;
            t1.x -= bb1.x; t1.y -= bb1.y; t1.z -= bb1.z; t1.w -= bb1.w;
            TF = pack8(t0, t1, lolane);
        }

        // ---- 5. GEMM2 per 16-col strip: X = y - t*C, in-place in yT ----
        float* yF = reinterpret_cast<float*>(&yT[wv][0][0]);
        #define STRIP(n) { \
            f32x4 x; \
            x[0] = yF[(4*lg + 0)*68 + (n)*16 + lh]; \
            x[1] = yF[(4*lg + 1)*68 + (n)*16 + lh]; \
            x[2] = yF[(4*lg + 2)*68 + (n)*16 + lh]; \
            x[3] = yF[(4*lg + 3)*68 + (n)*16 + lh]; \
            x = MF(TF, C1_##n, x); x = MF(TF, C2_##n, x); \
            yF[(4*lg + 0)*68 + (n)*16 + lh] = x[0]; \
            yF[(4*lg + 1)*68 + (n)*16 + lh] = x[1]; \
            yF[(4*lg + 2)*68 + (n)*16 + lh] = x[2]; \
            yF[(4*lg + 3)*68 + (n)*16 + lh] = x[3]; }
        STRIP(0) STRIP(1) STRIP(2) STRIP(3)
        #undef STRIP

        // ---- 6. coalesced stores: 4x1KB ----
        float4* odst = o4 + tile * 256;
        odst[l]       = yT[wv][0*4 + lg][lh];
        odst[64 + l]  = yT[wv][1*4 + lg][lh];
        odst[128 + l] = yT[wv][2*4 + lg][lh];
        odst[192 + l] = yT[wv][3*4 + lg][lh];
    }
}

// ---------------------------------------------------------------------------
extern "C" void kernel_launch(void* const* d_in, const int* in_sizes, int n_in,
                              void* d_out, int out_size, void* d_ws, size_t ws_size,
                              hipStream_t stream) {
    const float* y = (const float*)d_in[0];   // (1048576, 64)
    const float* A = (const float*)d_in[1];   // (16, 64)
    const float* b = (const float*)d_in[2];   // (1048576, 16)
    float* out = (float*)d_out;               // (1048576, 64)
    float* ws  = (float*)d_ws;                // 1024 floats: Ct (64x16)

    precompute_kernel<<<1, 256, 0, stream>>>(A, ws);
    // 1024 blocks x 4 waves = 4096 waves, 16 tiles each, 16 rows/tile.
    apply_kernel<<<1024, 256, 0, stream>>>(y, b, A, ws, out);
}